// Round 13
// baseline (110.357 us; speedup 1.0000x reference)
//
#include <hip/hip_runtime.h>
#include <hip/hip_bf16.h>
#include <stdint.h>

typedef __bf16 bf16;
typedef __attribute__((ext_vector_type(8)))  __bf16 bf16x8;
typedef __attribute__((ext_vector_type(16))) float  f32x16;
typedef __attribute__((ext_vector_type(4)))  float  f32x4v;
typedef __attribute__((ext_vector_type(2)))  float  f32x2v;

#define B_DIM 128
#define F_DIM 256
#define C_DIM 512
#define HID   2048
#define C2    256
#define MROWS 16384

// ws: w1pp 1MB | w2pp 1MB   (B-fragment-packed weights for 32x32x16 MFMA)
// pack: element W[n][k] -> frag=(n>>5)*NKF+(k>>4), lane=((k>>3)&1)<<5|(n&31), e=k&7
//       byte = frag*1024 + lane*16 + e*2     (NKF: W1'=16, W2=128)
static constexpr size_t OFF_W1 = 0;
static constexpr size_t OFF_W2 = 1u << 20;

__device__ __forceinline__ unsigned short bfbits(float f) {
    bf16 h = (bf16)f;
    return __builtin_bit_cast(unsigned short, h);
}

// ---------------- prep: fold interp into W1 + pack both weights as B-frags ----
__global__ __launch_bounds__(256) void prep_kernel(
    const float* __restrict__ w1, const float* __restrict__ w2,
    bf16* __restrict__ w1pp, bf16* __restrict__ w2pp)
{
    const int blk = blockIdx.x;
    const int t = threadIdx.x;
    if (blk < 2048) {
        int idx = blk * 256 + t;
        int h = idx >> 8, k = idx & 255;
        const float* wrow = w1 + (size_t)h * C_DIM;
        float acc = 0.f;
        int jlo = (k == 0) ? 0 : (int)((float)(k - 1) * (511.0f / 255.0f));
        int jhi = (int)((float)(k + 1) * (511.0f / 255.0f)) + 1;
        if (jhi > 511) jhi = 511;
        for (int j = jlo; j <= jhi; ++j) {
            float pos = (float)j * (255.0f / 511.0f);
            int i0 = (int)pos;
            if (i0 > 254) i0 = 254;
            float w = pos - (float)i0;
            float coef = (i0 == k) ? (1.0f - w) : ((i0 + 1 == k) ? w : 0.0f);
            acc += coef * wrow[j];
        }
        size_t frag = (size_t)(h >> 5) * 16 + (k >> 4);
        size_t lane = (size_t)(((k >> 3) & 1) << 5 | (h & 31));
        w1pp[frag * 512 + lane * 8 + (k & 7)] = (bf16)acc;
    } else {
        int idx2 = (blk - 2048) * 256 + t;     // 0..524287
        int c2 = idx2 >> 11, hid = idx2 & 2047;
        float v = w2[(size_t)c2 * HID + hid];
        size_t frag = (size_t)(c2 >> 5) * 128 + (hid >> 4);
        size_t lane = (size_t)(((hid >> 3) & 1) << 5 | (c2 & 31));
        w2pp[frag * 512 + lane * 8 + (hid & 7)] = (bf16)v;
    }
}

// ---------------- fused: DWT -> [G1 -> GELU -> G2] x 4 pairs -> iDWT ----------
// 512 blocks x 512 thr (8 waves), 32 rows/block, 2 blocks/CU (VGPR<=128, 48KB).
// Pair = 512 hid. G1: wave = 32 rows x 64 hid (nf=2). G2: wave = 32 rows x 32 c2
// over pair K=512. Zero weight duplication (2MB/block from L2). Weight frags
// flow through a CONTINUOUS rolling 4-slot register ring chained across all
// phases (plain loads). x/out use non-temporal hints so weights stay L2-hot.
__global__ __launch_bounds__(512, 4) void fused_mlp(
    const bf16* __restrict__ w1pp, const bf16* __restrict__ w2pp,
    const float* __restrict__ b1, const float* __restrict__ b2,
    const float* __restrict__ x, float* __restrict__ out)
{
    __shared__ __align__(16) char smem[49152];   // [0,16K) ll ; [16K,48K) Hs
    char* hsm = smem + 16384;

    const int tid = threadIdx.x;
    const int l   = tid & 63;
    const int wv  = tid >> 6;          // 0..7
    const int sub = wv >> 2;           // 0..1 : 256-chunk of the pair
    const int sl4 = wv & 3;            // 0..3 : 64-hid slot within chunk
    const int R0  = blockIdx.x * 32;
    const char* w1B = (const char*)w1pp;
    const char* w2B = (const char*)w2pp;

    // ---- ring preload: pair-0 G1 uses 0..3 (land under DWT) ----
    bf16x8 wf[4];
    {
        const char* w1f0 = w1B + (size_t)(sub * 8 + sl4 * 2) * 16 * 1024 + (size_t)l * 16;
        wf[0] = *(const bf16x8*)(w1f0);                     // ks0 nf0
        wf[1] = *(const bf16x8*)(w1f0 + 16 * 1024);         // ks0 nf1
        wf[2] = *(const bf16x8*)(w1f0 + 1024);              // ks1 nf0
        wf[3] = *(const bf16x8*)(w1f0 + 16 * 1024 + 1024);  // ks1 nf1
    }

    // ---- DWT: ll A-frag-packed into LDS (nt x-loads; conflict-free writes) ----
    {
        const int r = tid & 31;
        const int s = tid >> 5;                // 0..15
        const int gbf = R0 + r;
        const float* xr0 = x + ((size_t)(gbf >> 7) * F_DIM + (size_t)(gbf & 127) * 2) * C_DIM;
        const float* xr1 = xr0 + C_DIM;
#pragma unroll
        for (int jj = 0; jj < 2; ++jj) {
            int j = s * 2 + jj;                // c2 in [8j, 8j+8)
            f32x4v a[4], b[4];
#pragma unroll
            for (int i = 0; i < 4; ++i) {
                a[i] = __builtin_nontemporal_load((const f32x4v*)(xr0 + (j * 4 + i) * 4));
                b[i] = __builtin_nontemporal_load((const f32x4v*)(xr1 + (j * 4 + i) * 4));
            }
            const float* pa = (const float*)a;
            const float* pb = (const float*)b;
            bf16x8 pk;
#pragma unroll
            for (int e = 0; e < 8; ++e)
                pk[e] = (bf16)(0.5f * (pa[2*e] + pa[2*e+1] + pb[2*e] + pb[2*e+1]));
            *(bf16x8*)(smem + s * 1024 + (size_t)((jj << 5) | r) * 16) = pk;
        }
    }
    __syncthreads();

    f32x16 acc2{};

#pragma unroll 1
    for (int pc = 0; pc < 4; ++pc) {
        const char* w1f = w1B + (size_t)(pc * 16 + sub * 8 + sl4 * 2) * 16 * 1024 + (size_t)l * 16;
        const char* w2f = w2B + ((size_t)(wv * 128 + pc * 32)) * 1024 + (size_t)l * 16;
        const int pn = (pc + 1) & 3;
        const char* w1fn = w1B + (size_t)(pn * 16 + sub * 8 + sl4 * 2) * 16 * 1024 + (size_t)l * 16;

        // ===== GEMM1: acc1[nf] (32 rows x 64 hid), K=256 =====
        f32x16 acc1_0{}, acc1_1{};
#pragma unroll
        for (int ks = 0; ks < 16; ++ks) {
            bf16x8 af = *(const bf16x8*)(smem + ks * 1024 + (size_t)l * 16);
            acc1_0 = __builtin_amdgcn_mfma_f32_32x32x16_bf16(af, wf[(2 * ks) & 3], acc1_0, 0, 0, 0);
            acc1_1 = __builtin_amdgcn_mfma_f32_32x32x16_bf16(af, wf[(2 * ks + 1) & 3], acc1_1, 0, 0, 0);
            if (ks < 14) {             // refill with uses 2ks+4, 2ks+5 (ks+2's pair)
                wf[(2 * ks) & 3]     = *(const bf16x8*)(w1f + (ks + 2) * 1024);
                wf[(2 * ks + 1) & 3] = *(const bf16x8*)(w1f + 16 * 1024 + (ks + 2) * 1024);
            } else {                   // chain: G2 uses 0..3
                int v0 = (ks - 14) * 2;
                wf[(2 * ks) & 3]     = *(const bf16x8*)(w2f + (v0 + 0) * 1024);
                wf[(2 * ks + 1) & 3] = *(const bf16x8*)(w2f + (v0 + 1) * 1024);
            }
        }

        // ===== GELU(+bias) -> Hs (A-frag-packed; DPP lane^1 pair pack) =====
#pragma unroll
        for (int nf = 0; nf < 2; ++nf) {
            const f32x16& A = nf ? acc1_1 : acc1_0;
            const int cin = sub * 256 + sl4 * 64 + nf * 32 + (l & 31);  // hid in pair
            const float bs = b1[pc * 512 + cin];
            const int kf2 = cin >> 4;
#pragma unroll
            for (int reg = 0; reg < 16; ++reg) {
                float v = A[reg] + bs;
                float tt = v * (0.79788456080f + 0.03567740814f * v * v);
                float g = v / (1.0f + __expf(-2.0f * tt));
                float gp = __builtin_bit_cast(float,
                    __builtin_amdgcn_mov_dpp(__builtin_bit_cast(int, g), 0xB1, 0xF, 0xF, true));
                if (!(l & 1)) {
                    unsigned u = (unsigned)bfbits(g) | ((unsigned)bfbits(gp) << 16);
                    int crow = (reg & 3) + 8 * (reg >> 2) + 4 * (l >> 5);
                    int lane2 = (((l >> 3) & 1) << 5) | crow;
                    *(unsigned*)(hsm + kf2 * 1024 + lane2 * 16 + (l & 7) * 2) = u;
                }
            }
        }
        __syncthreads();               // Hs(pair) ready

        // ===== GEMM2: acc2 += Hs x W2, K=512 (32 ksteps), wave = 32 c2 =====
#pragma unroll
        for (int v = 0; v < 32; ++v) {
            bf16x8 hf = *(const bf16x8*)(hsm + v * 1024 + (size_t)l * 16);
            acc2 = __builtin_amdgcn_mfma_f32_32x32x16_bf16(hf, wf[v & 3], acc2, 0, 0, 0);
            if (v < 28) {
                wf[v & 3] = *(const bf16x8*)(w2f + (v + 4) * 1024);
            } else {                   // chain: next pair G1 uses 0..3
                int u = v - 28;
                wf[v & 3] = *(const bf16x8*)(w1fn + (u & 1) * 16 * 1024 + (u >> 1) * 1024);
            }
        }
        __syncthreads();               // Hs consumed before next pair's GELU
    }

    // ---- epilogue: bias + iDWT  (out = x + 0.5*(ll_new - ll_old)), nt I/O ----
    {
        const int c2 = wv * 32 + (l & 31);
        const float bs = b2[c2];
#pragma unroll
        for (int reg = 0; reg < 16; ++reg) {
            int R = R0 + (reg & 3) + 8 * (reg >> 2) + 4 * (l >> 5);
            int b = R >> 7, f2 = R & 127;
            const float* xr = x + ((size_t)b * F_DIM + (size_t)f2 * 2) * C_DIM;
            f32x2v p0 = __builtin_nontemporal_load((const f32x2v*)(xr + c2 * 2));
            f32x2v p1 = __builtin_nontemporal_load((const f32x2v*)(xr + C_DIM + c2 * 2));
            float llo = 0.5f * (p0[0] + p0[1] + p1[0] + p1[1]);
            float d = 0.5f * ((acc2[reg] + bs) - llo);
            f32x2v o0, o1;
            o0[0] = p0[0] + d; o0[1] = p0[1] + d;
            o1[0] = p1[0] + d; o1[1] = p1[1] + d;
            float* orow = out + ((size_t)b * F_DIM + (size_t)f2 * 2) * C_DIM;
            __builtin_nontemporal_store(o0, (f32x2v*)(orow + c2 * 2));
            __builtin_nontemporal_store(o1, (f32x2v*)(orow + C_DIM + c2 * 2));
        }
    }
}

extern "C" void kernel_launch(void* const* d_in, const int* in_sizes, int n_in,
                              void* d_out, int out_size, void* d_ws, size_t ws_size,
                              hipStream_t stream) {
    const float* x     = (const float*)d_in[0];
    const float* fc1_w = (const float*)d_in[1];
    const float* fc1_b = (const float*)d_in[2];
    const float* fc2_w = (const float*)d_in[3];
    const float* fc2_b = (const float*)d_in[4];
    float* out = (float*)d_out;

    char* ws = (char*)d_ws;
    bf16* w1pp = (bf16*)(ws + OFF_W1);
    bf16* w2pp = (bf16*)(ws + OFF_W2);

    prep_kernel<<<4096, 256, 0, stream>>>(fc1_w, fc2_w, w1pp, w2pp);
    fused_mlp<<<MROWS / 32, 512, 0, stream>>>(w1pp, w2pp, fc1_b, fc2_b, x, out);
}